// Round 21
// baseline (280.306 us; speedup 1.0000x reference)
//
#include <hip/hip_runtime.h>
#include <math.h>

constexpr int NN = 20000;   // nodes
constexpr int NE = 320000;  // edges
constexpr int MROWS = 20224; // A1/A3 row padding
constexpr int SB = 79;      // scan blocks (79*256 >= NN)

typedef __bf16 bf16x8 __attribute__((ext_vector_type(8)));
typedef float f32x4 __attribute__((ext_vector_type(4)));

__device__ __forceinline__ unsigned short f2bf(float f) {
  unsigned int u = __float_as_uint(f);
  unsigned int r = (u + 0x7FFFu + ((u >> 16) & 1u)) >> 16;
  return (unsigned short)r;
}

// ---------------- fast zero ----------------
__global__ __launch_bounds__(256) void zero_kernel(int4* __restrict__ p, int n4) {
  int i = blockIdx.x * 256 + threadIdx.x;
  if (i < n4) p[i] = make_int4(0, 0, 0, 0);
}

// ---------------- degree count ----------------
__global__ void deg_count_kernel(const int* __restrict__ src, const int* __restrict__ dst,
                                 int* __restrict__ degs, int* __restrict__ degd, int nE) {
  int e = blockIdx.x * blockDim.x + threadIdx.x;
  if (e < nE) {
    atomicAdd(degs + src[e], 1);
    atomicAdd(degd + dst[e], 1);
  }
}

// ---------------- scan phase B ----------------
__global__ __launch_bounds__(256) void pscan_norm_kernel(
    const int* __restrict__ degs, const int* __restrict__ degd,
    int* __restrict__ pscan, int* __restrict__ bsum,
    float* __restrict__ ns, float* __restrict__ nd, int n) {
  __shared__ int s[256];
  int t = threadIdx.x;
  int idx = blockIdx.x * 256 + t;
  int val = 0;
  if (idx < n) {
    int dd = degd[idx];
    val = dd;
    ns[idx] = rsqrtf(fmaxf((float)degs[idx], 1.0f));
    nd[idx] = rsqrtf(fmaxf((float)dd, 1.0f));
  }
  s[t] = val;
  __syncthreads();
#pragma unroll
  for (int off = 1; off < 256; off <<= 1) {
    int v = (t >= off) ? s[t - off] : 0;
    __syncthreads();
    s[t] += v;
    __syncthreads();
  }
  if (idx < n) pscan[idx] = s[t] - val;
  if (t == 255) bsum[blockIdx.x] = s[255];
}

// ---------------- scan phase C+D fused ----------------
__global__ __launch_bounds__(256) void rowptr_fix_kernel(
    const int* __restrict__ pscan, const int* __restrict__ bsum,
    int* __restrict__ rowptr, int n) {
  __shared__ int s[128];
  int t = threadIdx.x;
  if (t < 128) s[t] = (t < SB) ? bsum[t] : 0;
  __syncthreads();
#pragma unroll
  for (int off = 1; off < 128; off <<= 1) {
    int v = (t < 128 && t >= off) ? s[t - off] : 0;
    __syncthreads();
    if (t < 128) s[t] += v;
    __syncthreads();
  }
  int idx = blockIdx.x * 256 + t;
  int boff = (blockIdx.x == 0) ? 0 : s[blockIdx.x - 1];
  if (idx < n) rowptr[idx] = pscan[idx] + boff;
  if (idx == 0) rowptr[n] = NE;
}

// ---------------- CSR fill ----------------
__global__ void csr_fill_kernel(const int* __restrict__ src, const int* __restrict__ dst,
                                const int* __restrict__ rowptr, int* __restrict__ cursor,
                                int* __restrict__ col, int nE) {
  int e = blockIdx.x * blockDim.x + threadIdx.x;
  if (e < nE) {
    int d = dst[e];
    int p = atomicAdd(cursor + d, 1);
    col[rowptr[d] + p] = src[e];
  }
}

// ---------------- tiled-transpose weight convert (coalesced both sides) -----------
__global__ __launch_bounds__(256) void wt_tconv_kernel(
    const float* __restrict__ W1, const float* __restrict__ W2,
    const float* __restrict__ W3, const float* __restrict__ W4,
    unsigned short* __restrict__ W1t, unsigned short* __restrict__ W2t,
    unsigned short* __restrict__ W3t, unsigned short* __restrict__ W4t) {
  __shared__ float tile[32][33];
  int b = blockIdx.x;
  const float* W; unsigned short* Wt; int K, N, Kpad, tn, tile_id;
  if (b < 208)      { W = W1; Wt = W1t; K = 256; N = 800; Kpad = 256; tn = 26; tile_id = b; }
  else if (b < 312) { W = W2; Wt = W2t; K = 800; N = 128; Kpad = 832; tn = 4;  tile_id = b - 208; }
  else if (b < 416) { W = W3; Wt = W3t; K = 128; N = 800; Kpad = 128; tn = 26; tile_id = b - 312; }
  else              { W = W4; Wt = W4t; K = 800; N = 256; Kpad = 832; tn = 8;  tile_id = b - 416; }
  int kt = tile_id / tn, nt = tile_id - kt * tn;
  int tx = threadIdx.x & 31, ty = threadIdx.x >> 5;
#pragma unroll
  for (int i = 0; i < 4; ++i) {
    int k = kt * 32 + ty + i * 8;
    int n = nt * 32 + tx;
    tile[ty + i * 8][tx] = (k < K && n < N) ? W[(size_t)k * N + n] : 0.f;
  }
  __syncthreads();
#pragma unroll
  for (int i = 0; i < 4; ++i) {
    int nl = ty + i * 8;
    int row = nt * 32 + nl;
    int colk = kt * 32 + tx;
    Wt[(size_t)row * Kpad + colk] = f2bf(tile[tx][nl]);
  }
}

// ---------------- xb = bf16(x * ns[row]) ----------------
__global__ __launch_bounds__(256) void scale_cvt_kernel(
    const float* __restrict__ x, const float* __restrict__ ns,
    unsigned short* __restrict__ xb) {
  int t = blockIdx.x * 256 + threadIdx.x;
  if (t >= NN * 32) return;
  int node = t >> 5;
  float sc = ns[node];
  float4 v1 = reinterpret_cast<const float4*>(x)[t * 2];
  float4 v2 = reinterpret_cast<const float4*>(x)[t * 2 + 1];
  uint4 o;
  o.x = f2bf(v1.x * sc) | ((unsigned)f2bf(v1.y * sc) << 16);
  o.y = f2bf(v1.z * sc) | ((unsigned)f2bf(v1.w * sc) << 16);
  o.z = f2bf(v2.x * sc) | ((unsigned)f2bf(v2.y * sc) << 16);
  o.w = f2bf(v2.z * sc) | ((unsigned)f2bf(v2.w * sc) << 16);
  reinterpret_cast<uint4*>(xb)[t] = o;
}

// ---------------- bf16 CSR gather (edge loop unrolled x2) ----------------
template <int F, int EPI>
__global__ __launch_bounds__(256) void gatherb_kernel(
    const unsigned short* __restrict__ in, const int* __restrict__ rowptr,
    const int* __restrict__ col, const float* __restrict__ sDst,
    const float* __restrict__ bias, const float* __restrict__ snext,
    unsigned short* __restrict__ out, float* __restrict__ out2, int n) {
  constexpr int LPN = F / 8;
  constexpr int NPB = 256 / LPN;
  const int tid = threadIdx.x;
  const int node = blockIdx.x * NPB + tid / LPN;
  const int j = tid % LPN;
  if (node >= n) return;
  const int e0 = rowptr[node], e1 = rowptr[node + 1];
  float a[8] = {0.f, 0.f, 0.f, 0.f, 0.f, 0.f, 0.f, 0.f};
  int e = e0;
  for (; e + 1 < e1; e += 2) {
    int c0 = col[e], c1 = col[e + 1];
    uint4 u0 = *reinterpret_cast<const uint4*>(in + (size_t)c0 * F + j * 8);
    uint4 u1 = *reinterpret_cast<const uint4*>(in + (size_t)c1 * F + j * 8);
    a[0] += __uint_as_float(u0.x << 16);
    a[1] += __uint_as_float(u0.x & 0xffff0000u);
    a[2] += __uint_as_float(u0.y << 16);
    a[3] += __uint_as_float(u0.y & 0xffff0000u);
    a[4] += __uint_as_float(u0.z << 16);
    a[5] += __uint_as_float(u0.z & 0xffff0000u);
    a[6] += __uint_as_float(u0.w << 16);
    a[7] += __uint_as_float(u0.w & 0xffff0000u);
    a[0] += __uint_as_float(u1.x << 16);
    a[1] += __uint_as_float(u1.x & 0xffff0000u);
    a[2] += __uint_as_float(u1.y << 16);
    a[3] += __uint_as_float(u1.y & 0xffff0000u);
    a[4] += __uint_as_float(u1.z << 16);
    a[5] += __uint_as_float(u1.z & 0xffff0000u);
    a[6] += __uint_as_float(u1.w << 16);
    a[7] += __uint_as_float(u1.w & 0xffff0000u);
  }
  if (e < e1) {
    int c = col[e];
    uint4 u = *reinterpret_cast<const uint4*>(in + (size_t)c * F + j * 8);
    a[0] += __uint_as_float(u.x << 16);
    a[1] += __uint_as_float(u.x & 0xffff0000u);
    a[2] += __uint_as_float(u.y << 16);
    a[3] += __uint_as_float(u.y & 0xffff0000u);
    a[4] += __uint_as_float(u.z << 16);
    a[5] += __uint_as_float(u.z & 0xffff0000u);
    a[6] += __uint_as_float(u.w << 16);
    a[7] += __uint_as_float(u.w & 0xffff0000u);
  }
  if (EPI == 0) {
    uint4 o;
    o.x = f2bf(a[0]) | ((unsigned)f2bf(a[1]) << 16);
    o.y = f2bf(a[2]) | ((unsigned)f2bf(a[3]) << 16);
    o.z = f2bf(a[4]) | ((unsigned)f2bf(a[5]) << 16);
    o.w = f2bf(a[6]) | ((unsigned)f2bf(a[7]) << 16);
    *reinterpret_cast<uint4*>(out + (size_t)node * F + j * 8) = o;
    return;
  }
  const float sd = sDst[node];
  float v[8];
#pragma unroll
  for (int k = 0; k < 8; ++k) v[k] = a[k] * sd + bias[j * 8 + k];
  if (EPI == 1) {
    float sn = snext[node];
    uint4 o;
    o.x = f2bf(v[0] * sn) | ((unsigned)f2bf(v[1] * sn) << 16);
    o.y = f2bf(v[2] * sn) | ((unsigned)f2bf(v[3] * sn) << 16);
    o.z = f2bf(v[4] * sn) | ((unsigned)f2bf(v[5] * sn) << 16);
    o.w = f2bf(v[6] * sn) | ((unsigned)f2bf(v[7] * sn) << 16);
    *reinterpret_cast<uint4*>(out + (size_t)node * F + j * 8) = o;
  }
  float4 s1, s2;
  s1.x = 1.0f / (1.0f + expf(-v[0]));
  s1.y = 1.0f / (1.0f + expf(-v[1]));
  s1.z = 1.0f / (1.0f + expf(-v[2]));
  s1.w = 1.0f / (1.0f + expf(-v[3]));
  s2.x = 1.0f / (1.0f + expf(-v[4]));
  s2.y = 1.0f / (1.0f + expf(-v[5]));
  s2.z = 1.0f / (1.0f + expf(-v[6]));
  s2.w = 1.0f / (1.0f + expf(-v[7]));
  *reinterpret_cast<float4*>(out2 + (size_t)node * F + j * 8) = s1;
  *reinterpret_cast<float4*>(out2 + (size_t)node * F + j * 8 + 4) = s2;
}

// ================= gemm9v4: r18-best fused GEMM + per-block nt ROTATION ===========
// Identical math/staging to gemm9v3, but block b processes hidden n-tiles in the
// rotated order (b%13, b%13+1, ..., mod 13). De-phase-locks concurrent blocks so
// L2 weight reads spread across the whole 624KB range instead of hammering one
// 48KB window (suspected L2-slice hotspot behind the 48us floor). acc2 is an
// nt-sum: per-block order fixed -> deterministic; rounding within tolerance.
template <int KT1, int NOUT>
__global__ __launch_bounds__(128) void gemm9v4_kernel(
    const unsigned short* __restrict__ A,    // [MROWS][K1] bf16
    const unsigned short* __restrict__ Wa,   // [832][K1] bf16
    const unsigned short* __restrict__ Wb,   // [N2][832] bf16
    unsigned short* __restrict__ Out,        // [NN][N2] bf16
    int M, const float* __restrict__ nd, const float* __restrict__ ns,
    const float* __restrict__ ba) {
  constexpr int K1 = KT1 * 32;
  constexpr int N2 = NOUT * 16;
  constexpr int ROWB1 = K1 * 2;
  constexpr int CPR1 = K1 / 8;
  constexpr int W1B = 64 * ROWB1;
  constexpr int W2B = N2 * 128;
  constexpr int HST = 144;
  __shared__ __align__(16) char lds[W1B + W2B + 2 * 16 * HST];

  const int tid = threadIdx.x;
  const int l = tid & 63, w = tid >> 6;     // 2 waves
  const int lrow = l & 15, k16 = l >> 4;
  const int m0 = blockIdx.x * 32 + w * 16;
  const int nt0 = blockIdx.x % 13;          // per-block rotation offset
  char* const w1p = lds;
  char* const w2s = lds + W1B;
  char* const h1t = lds + W1B + W2B + w * 16 * HST;

  auto stage = [&](int nt) {
#pragma unroll
    for (int i = 0; i < 64 * CPR1 / 128; ++i) {
      int c = i * 128 + tid;
      int row = c / CPR1, lch = c % CPR1;
      int gch = (lch & ~7) | ((lch & 7) ^ (row & 7));
      const unsigned short* gp = Wa + (size_t)(nt * 64 + row) * K1 + gch * 8;
      __builtin_amdgcn_global_load_lds(
          (const __attribute__((address_space(1))) void*)gp,
          (__attribute__((address_space(3))) void*)(w1p + (i * 128 + w * 64) * 16), 16, 0, 0);
    }
#pragma unroll
    for (int i = 0; i < N2 * 8 / 128; ++i) {
      int c = i * 128 + tid;
      int row = c >> 3, lch = c & 7;
      int gch = lch ^ (row & 7);
      const unsigned short* gp = Wb + (size_t)row * 832 + nt * 64 + gch * 8;
      __builtin_amdgcn_global_load_lds(
          (const __attribute__((address_space(1))) void*)gp,
          (__attribute__((address_space(3))) void*)(w2s + (i * 128 + w * 64) * 16), 16, 0, 0);
    }
  };

  // ---- per-wave A band: 16 rows x K1 in registers ----
  bf16x8 af[KT1];
#pragma unroll
  for (int t = 0; t < KT1; ++t)
    af[t] = *reinterpret_cast<const bf16x8*>(
        A + (size_t)(m0 + lrow) * K1 + t * 32 + k16 * 8);

  stage(nt0);
  __syncthreads();

  f32x4 acc2[NOUT] = {};
  for (int p = 0; p < 13; ++p) {
    int nt = nt0 + p;
    if (nt >= 13) nt -= 13;
    // ---- gemm1: acc1 = Aband @ WaPanel^T ----
    f32x4 acc1[4] = {};
#pragma unroll
    for (int t = 0; t < KT1; ++t) {
      bf16x8 bf[4];
#pragma unroll
      for (int ni = 0; ni < 4; ++ni) {
        int row = ni * 16 + lrow;
        int ch = t * 4 + k16;
        int sc = (ch & ~7) | ((ch & 7) ^ (row & 7));
        bf[ni] = *reinterpret_cast<const bf16x8*>(w1p + row * ROWB1 + sc * 16);
      }
#pragma unroll
      for (int ni = 0; ni < 4; ++ni)
        acc1[ni] = __builtin_amdgcn_mfma_f32_16x16x32_bf16(af[t], bf[ni], acc1[ni], 0, 0, 0);
    }

    // ---- epilogue-1: relu(nd*acc1 + b) -> per-wave H tile (padded stride) ----
#pragma unroll
    for (int q = 0; q < 4; ++q) {
      int rl = k16 * 4 + q;
      float rs = nd[m0 + rl];
#pragma unroll
      for (int ni = 0; ni < 4; ++ni) {
        int colc = ni * 16 + lrow;
        int jg = nt * 64 + colc;
        float bb = (jg < 800) ? ba[jg] : 0.f;
        float v = fmaxf(acc1[ni][q] * rs + bb, 0.f);
        *(unsigned short*)(h1t + rl * HST + (colc >> 3) * 16 + (colc & 7) * 2) = f2bf(v);
      }
    }

    // ---- gemm2: acc2 += Htile @ WbSlice^T (same-wave LDS RAW via lgkmcnt) ----
#pragma unroll
    for (int ks = 0; ks < 2; ++ks) {
      bf16x8 a2 = *reinterpret_cast<const bf16x8*>(h1t + lrow * HST + (ks * 4 + k16) * 16);
#pragma unroll
      for (int ni = 0; ni < NOUT; ++ni) {
        int rc = ni * 16 + lrow;
        int sc = (ks * 4 + k16) ^ (rc & 7);
        bf16x8 b2v = *reinterpret_cast<const bf16x8*>(w2s + rc * 128 + sc * 16);
        acc2[ni] = __builtin_amdgcn_mfma_f32_16x16x32_bf16(a2, b2v, acc2[ni], 0, 0, 0);
      }
    }
    __syncthreads();
    if (p + 1 < 13) {
      int ntn = nt + 1 == 13 ? 0 : nt + 1;
      stage(ntn);
      __syncthreads();
    }
  }

  // ---- epilogue-2: Out = bf16(acc2 * ns[r]) ----
#pragma unroll
  for (int q = 0; q < 4; ++q) {
    int r = m0 + k16 * 4 + q;
    if (r >= M) continue;
    float sn = ns[r];
#pragma unroll
    for (int ni = 0; ni < NOUT; ++ni) {
      int c = ni * 16 + lrow;
      Out[(size_t)r * N2 + c] = f2bf(acc2[ni][q] * sn);
    }
  }
}

extern "C" void kernel_launch(void* const* d_in, const int* in_sizes, int n_in,
                              void* d_out, int out_size, void* d_ws, size_t ws_size,
                              hipStream_t stream) {
  const float* x  = (const float*)d_in[0];
  const int* src  = (const int*)d_in[1];
  const int* dst  = (const int*)d_in[2];
  const float* W1 = (const float*)d_in[3];
  const float* b1 = (const float*)d_in[4];
  const float* W2 = (const float*)d_in[5];
  const float* b2 = (const float*)d_in[6];
  const float* W3 = (const float*)d_in[7];
  const float* b3 = (const float*)d_in[8];
  const float* W4 = (const float*)d_in[9];
  const float* b4 = (const float*)d_in[10];

  float* out_enc = (float*)d_out;                  // [NN,128]
  float* out_dec = out_enc + (size_t)NN * 128;     // [NN,256]

  // ---- workspace layout (~50 MB) ----
  float* ns = (float*)d_ws;                        // [NN]
  float* nd = ns + NN;                             // [NN]
  unsigned short* xb  = (unsigned short*)(nd + NN);  // [NN*256]
  unsigned short* T2b = xb + (size_t)NN * 256;     // [NN*128] bf16 (L1+L2 out)
  unsigned short* h2  = T2b + (size_t)NN * 128;    // [NN*128] bf16 (h2*ns)
  unsigned short* A1  = h2 + (size_t)NN * 128;     // [MROWS*256]
  unsigned short* A3  = A1 + (size_t)MROWS * 256;  // [MROWS*128]
  unsigned short* G4  = A3 + (size_t)MROWS * 128;  // [NN*256] bf16 (L3+L4 out)
  unsigned short* W1t = G4 + (size_t)NN * 256;     // [832*256]
  unsigned short* W2t = W1t + 832 * 256;           // [128*832]
  unsigned short* W3t = W2t + 128 * 832;           // [832*128]
  unsigned short* W4t = W3t + 832 * 128;           // [256*832]
  int* degs   = (int*)(W4t + 256 * 832);           // [NN]
  int* degd   = degs + NN;                         // [NN]
  int* cursor = degd + NN;                         // [NN]
  int* rowptr = cursor + NN;                       // [NN+1]
  int* col    = rowptr + NN + 1;                   // [NE]
  int* pscan  = col + NE;                          // [NN]
  int* bsum   = pscan + NN;                        // [SB]

  // ---- CSR build + norms (parallel scan) ----
  zero_kernel<<<(3 * NN / 4 + 255) / 256, 256, 0, stream>>>((int4*)degs, 3 * NN / 4);
  deg_count_kernel<<<(NE + 255) / 256, 256, 0, stream>>>(src, dst, degs, degd, NE);
  pscan_norm_kernel<<<SB, 256, 0, stream>>>(degs, degd, pscan, bsum, ns, nd, NN);
  rowptr_fix_kernel<<<SB, 256, 0, stream>>>(pscan, bsum, rowptr, NN);
  csr_fill_kernel<<<(NE + 255) / 256, 256, 0, stream>>>(src, dst, rowptr, cursor, col, NE);

  // ---- weight conversion: tiled transpose ----
  wt_tconv_kernel<<<624, 256, 0, stream>>>(W1, W2, W3, W4, W1t, W2t, W3t, W4t);

  // ---- L1+L2 fused: xb -> gather -> A1; gemm9v4<8,8> -> T2b ----
  scale_cvt_kernel<<<(NN * 32 + 255) / 256, 256, 0, stream>>>(x, ns, xb);
  gatherb_kernel<256, 0><<<(NN + 7) / 8, 256, 0, stream>>>(
      xb, rowptr, col, nullptr, nullptr, nullptr, A1, nullptr, NN);
  gemm9v4_kernel<8, 8><<<628, 128, 0, stream>>>(A1, W1t, W2t, T2b, NN, nd, ns, b1);

  // ---- L2 gather: -> h2s=bf16(h2*ns) + sigmoid(out_enc) ----
  gatherb_kernel<128, 1><<<(NN + 15) / 16, 256, 0, stream>>>(
      T2b, rowptr, col, nd, b2, ns, h2, out_enc, NN);

  // ---- L3+L4 fused: gather(h2s) -> A3; gemm9v4<4,16> -> G4 ----
  gatherb_kernel<128, 0><<<(NN + 15) / 16, 256, 0, stream>>>(
      h2, rowptr, col, nullptr, nullptr, nullptr, A3, nullptr, NN);
  gemm9v4_kernel<4, 16><<<628, 128, 0, stream>>>(A3, W3t, W4t, G4, NN, nd, ns, b3);

  // ---- L4 gather: -> sigmoid(out_dec) ----
  gatherb_kernel<256, 2><<<(NN + 7) / 8, 256, 0, stream>>>(
      G4, rowptr, col, nd, b4, nullptr, nullptr, out_dec, NN);
}

// Round 22
// 239.437 us; speedup vs baseline: 1.1707x; 1.1707x over previous
//
#include <hip/hip_runtime.h>
#include <math.h>

constexpr int NN = 20000;   // nodes
constexpr int NE = 320000;  // edges
constexpr int MROWS = 20224; // A1/A3 row padding
constexpr int SB = 79;      // scan blocks (79*256 >= NN)

typedef __bf16 bf16x8 __attribute__((ext_vector_type(8)));
typedef float f32x4 __attribute__((ext_vector_type(4)));

__device__ __forceinline__ unsigned short f2bf(float f) {
  unsigned int u = __float_as_uint(f);
  unsigned int r = (u + 0x7FFFu + ((u >> 16) & 1u)) >> 16;
  return (unsigned short)r;
}

// ---------------- fast zero ----------------
__global__ __launch_bounds__(256) void zero_kernel(int4* __restrict__ p, int n4) {
  int i = blockIdx.x * 256 + threadIdx.x;
  if (i < n4) p[i] = make_int4(0, 0, 0, 0);
}

// ---------------- degree count ----------------
__global__ void deg_count_kernel(const int* __restrict__ src, const int* __restrict__ dst,
                                 int* __restrict__ degs, int* __restrict__ degd, int nE) {
  int e = blockIdx.x * blockDim.x + threadIdx.x;
  if (e < nE) {
    atomicAdd(degs + src[e], 1);
    atomicAdd(degd + dst[e], 1);
  }
}

// ---------------- scan phase B ----------------
__global__ __launch_bounds__(256) void pscan_norm_kernel(
    const int* __restrict__ degs, const int* __restrict__ degd,
    int* __restrict__ pscan, int* __restrict__ bsum,
    float* __restrict__ ns, float* __restrict__ nd, int n) {
  __shared__ int s[256];
  int t = threadIdx.x;
  int idx = blockIdx.x * 256 + t;
  int val = 0;
  if (idx < n) {
    int dd = degd[idx];
    val = dd;
    ns[idx] = rsqrtf(fmaxf((float)degs[idx], 1.0f));
    nd[idx] = rsqrtf(fmaxf((float)dd, 1.0f));
  }
  s[t] = val;
  __syncthreads();
#pragma unroll
  for (int off = 1; off < 256; off <<= 1) {
    int v = (t >= off) ? s[t - off] : 0;
    __syncthreads();
    s[t] += v;
    __syncthreads();
  }
  if (idx < n) pscan[idx] = s[t] - val;
  if (t == 255) bsum[blockIdx.x] = s[255];
}

// ---------------- scan phase C+D fused ----------------
__global__ __launch_bounds__(256) void rowptr_fix_kernel(
    const int* __restrict__ pscan, const int* __restrict__ bsum,
    int* __restrict__ rowptr, int n) {
  __shared__ int s[128];
  int t = threadIdx.x;
  if (t < 128) s[t] = (t < SB) ? bsum[t] : 0;
  __syncthreads();
#pragma unroll
  for (int off = 1; off < 128; off <<= 1) {
    int v = (t < 128 && t >= off) ? s[t - off] : 0;
    __syncthreads();
    if (t < 128) s[t] += v;
    __syncthreads();
  }
  int idx = blockIdx.x * 256 + t;
  int boff = (blockIdx.x == 0) ? 0 : s[blockIdx.x - 1];
  if (idx < n) rowptr[idx] = pscan[idx] + boff;
  if (idx == 0) rowptr[n] = NE;
}

// ---------------- CSR fill ----------------
__global__ void csr_fill_kernel(const int* __restrict__ src, const int* __restrict__ dst,
                                const int* __restrict__ rowptr, int* __restrict__ cursor,
                                int* __restrict__ col, int nE) {
  int e = blockIdx.x * blockDim.x + threadIdx.x;
  if (e < nE) {
    int d = dst[e];
    int p = atomicAdd(cursor + d, 1);
    col[rowptr[d] + p] = src[e];
  }
}

// ---------------- tiled-transpose weight convert (coalesced both sides) -----------
__global__ __launch_bounds__(256) void wt_tconv_kernel(
    const float* __restrict__ W1, const float* __restrict__ W2,
    const float* __restrict__ W3, const float* __restrict__ W4,
    unsigned short* __restrict__ W1t, unsigned short* __restrict__ W2t,
    unsigned short* __restrict__ W3t, unsigned short* __restrict__ W4t) {
  __shared__ float tile[32][33];
  int b = blockIdx.x;
  const float* W; unsigned short* Wt; int K, N, Kpad, tn, tile_id;
  if (b < 208)      { W = W1; Wt = W1t; K = 256; N = 800; Kpad = 256; tn = 26; tile_id = b; }
  else if (b < 312) { W = W2; Wt = W2t; K = 800; N = 128; Kpad = 832; tn = 4;  tile_id = b - 208; }
  else if (b < 416) { W = W3; Wt = W3t; K = 128; N = 800; Kpad = 128; tn = 26; tile_id = b - 312; }
  else              { W = W4; Wt = W4t; K = 800; N = 256; Kpad = 832; tn = 8;  tile_id = b - 416; }
  int kt = tile_id / tn, nt = tile_id - kt * tn;
  int tx = threadIdx.x & 31, ty = threadIdx.x >> 5;
#pragma unroll
  for (int i = 0; i < 4; ++i) {
    int k = kt * 32 + ty + i * 8;
    int n = nt * 32 + tx;
    tile[ty + i * 8][tx] = (k < K && n < N) ? W[(size_t)k * N + n] : 0.f;
  }
  __syncthreads();
#pragma unroll
  for (int i = 0; i < 4; ++i) {
    int nl = ty + i * 8;
    int row = nt * 32 + nl;
    int colk = kt * 32 + tx;
    Wt[(size_t)row * Kpad + colk] = f2bf(tile[tx][nl]);
  }
}

// ---------------- xb = bf16(x * ns[row]) ----------------
__global__ __launch_bounds__(256) void scale_cvt_kernel(
    const float* __restrict__ x, const float* __restrict__ ns,
    unsigned short* __restrict__ xb) {
  int t = blockIdx.x * 256 + threadIdx.x;
  if (t >= NN * 32) return;
  int node = t >> 5;
  float sc = ns[node];
  float4 v1 = reinterpret_cast<const float4*>(x)[t * 2];
  float4 v2 = reinterpret_cast<const float4*>(x)[t * 2 + 1];
  uint4 o;
  o.x = f2bf(v1.x * sc) | ((unsigned)f2bf(v1.y * sc) << 16);
  o.y = f2bf(v1.z * sc) | ((unsigned)f2bf(v1.w * sc) << 16);
  o.z = f2bf(v2.x * sc) | ((unsigned)f2bf(v2.y * sc) << 16);
  o.w = f2bf(v2.z * sc) | ((unsigned)f2bf(v2.w * sc) << 16);
  reinterpret_cast<uint4*>(xb)[t] = o;
}

// ---------------- bf16 CSR gather (edge loop unrolled x2) ----------------
template <int F, int EPI>
__global__ __launch_bounds__(256) void gatherb_kernel(
    const unsigned short* __restrict__ in, const int* __restrict__ rowptr,
    const int* __restrict__ col, const float* __restrict__ sDst,
    const float* __restrict__ bias, const float* __restrict__ snext,
    unsigned short* __restrict__ out, float* __restrict__ out2, int n) {
  constexpr int LPN = F / 8;
  constexpr int NPB = 256 / LPN;
  const int tid = threadIdx.x;
  const int node = blockIdx.x * NPB + tid / LPN;
  const int j = tid % LPN;
  if (node >= n) return;
  const int e0 = rowptr[node], e1 = rowptr[node + 1];
  float a[8] = {0.f, 0.f, 0.f, 0.f, 0.f, 0.f, 0.f, 0.f};
  int e = e0;
  for (; e + 1 < e1; e += 2) {
    int c0 = col[e], c1 = col[e + 1];
    uint4 u0 = *reinterpret_cast<const uint4*>(in + (size_t)c0 * F + j * 8);
    uint4 u1 = *reinterpret_cast<const uint4*>(in + (size_t)c1 * F + j * 8);
    a[0] += __uint_as_float(u0.x << 16);
    a[1] += __uint_as_float(u0.x & 0xffff0000u);
    a[2] += __uint_as_float(u0.y << 16);
    a[3] += __uint_as_float(u0.y & 0xffff0000u);
    a[4] += __uint_as_float(u0.z << 16);
    a[5] += __uint_as_float(u0.z & 0xffff0000u);
    a[6] += __uint_as_float(u0.w << 16);
    a[7] += __uint_as_float(u0.w & 0xffff0000u);
    a[0] += __uint_as_float(u1.x << 16);
    a[1] += __uint_as_float(u1.x & 0xffff0000u);
    a[2] += __uint_as_float(u1.y << 16);
    a[3] += __uint_as_float(u1.y & 0xffff0000u);
    a[4] += __uint_as_float(u1.z << 16);
    a[5] += __uint_as_float(u1.z & 0xffff0000u);
    a[6] += __uint_as_float(u1.w << 16);
    a[7] += __uint_as_float(u1.w & 0xffff0000u);
  }
  if (e < e1) {
    int c = col[e];
    uint4 u = *reinterpret_cast<const uint4*>(in + (size_t)c * F + j * 8);
    a[0] += __uint_as_float(u.x << 16);
    a[1] += __uint_as_float(u.x & 0xffff0000u);
    a[2] += __uint_as_float(u.y << 16);
    a[3] += __uint_as_float(u.y & 0xffff0000u);
    a[4] += __uint_as_float(u.z << 16);
    a[5] += __uint_as_float(u.z & 0xffff0000u);
    a[6] += __uint_as_float(u.w << 16);
    a[7] += __uint_as_float(u.w & 0xffff0000u);
  }
  if (EPI == 0) {
    uint4 o;
    o.x = f2bf(a[0]) | ((unsigned)f2bf(a[1]) << 16);
    o.y = f2bf(a[2]) | ((unsigned)f2bf(a[3]) << 16);
    o.z = f2bf(a[4]) | ((unsigned)f2bf(a[5]) << 16);
    o.w = f2bf(a[6]) | ((unsigned)f2bf(a[7]) << 16);
    *reinterpret_cast<uint4*>(out + (size_t)node * F + j * 8) = o;
    return;
  }
  const float sd = sDst[node];
  float v[8];
#pragma unroll
  for (int k = 0; k < 8; ++k) v[k] = a[k] * sd + bias[j * 8 + k];
  if (EPI == 1) {
    float sn = snext[node];
    uint4 o;
    o.x = f2bf(v[0] * sn) | ((unsigned)f2bf(v[1] * sn) << 16);
    o.y = f2bf(v[2] * sn) | ((unsigned)f2bf(v[3] * sn) << 16);
    o.z = f2bf(v[4] * sn) | ((unsigned)f2bf(v[5] * sn) << 16);
    o.w = f2bf(v[6] * sn) | ((unsigned)f2bf(v[7] * sn) << 16);
    *reinterpret_cast<uint4*>(out + (size_t)node * F + j * 8) = o;
  }
  float4 s1, s2;
  s1.x = 1.0f / (1.0f + expf(-v[0]));
  s1.y = 1.0f / (1.0f + expf(-v[1]));
  s1.z = 1.0f / (1.0f + expf(-v[2]));
  s1.w = 1.0f / (1.0f + expf(-v[3]));
  s2.x = 1.0f / (1.0f + expf(-v[4]));
  s2.y = 1.0f / (1.0f + expf(-v[5]));
  s2.z = 1.0f / (1.0f + expf(-v[6]));
  s2.w = 1.0f / (1.0f + expf(-v[7]));
  *reinterpret_cast<float4*>(out2 + (size_t)node * F + j * 8) = s1;
  *reinterpret_cast<float4*>(out2 + (size_t)node * F + j * 8 + 4) = s2;
}

// ================= gemm9v3: fused back-to-back GEMM, 2-wave blocks (r18/r20 best) ==
// Out[r][c] = ns[r] * SUM_j relu(nd[r]*(A[r,:].Wa[j,:]) + ba[j]) * Wb[c][j]
// Sequential nt order (lockstep across blocks keeps the shared 48KB weight window
// L2-hot -- r21 proved de-phasing costs 1.75x).
template <int KT1, int NOUT>
__global__ __launch_bounds__(128) void gemm9v3_kernel(
    const unsigned short* __restrict__ A,    // [MROWS][K1] bf16
    const unsigned short* __restrict__ Wa,   // [832][K1] bf16
    const unsigned short* __restrict__ Wb,   // [N2][832] bf16
    unsigned short* __restrict__ Out,        // [NN][N2] bf16
    int M, const float* __restrict__ nd, const float* __restrict__ ns,
    const float* __restrict__ ba) {
  constexpr int K1 = KT1 * 32;
  constexpr int N2 = NOUT * 16;
  constexpr int ROWB1 = K1 * 2;
  constexpr int CPR1 = K1 / 8;
  constexpr int W1B = 64 * ROWB1;
  constexpr int W2B = N2 * 128;
  constexpr int HST = 144;
  __shared__ __align__(16) char lds[W1B + W2B + 2 * 16 * HST];

  const int tid = threadIdx.x;
  const int l = tid & 63, w = tid >> 6;     // 2 waves
  const int lrow = l & 15, k16 = l >> 4;
  const int m0 = blockIdx.x * 32 + w * 16;
  char* const w1p = lds;
  char* const w2s = lds + W1B;
  char* const h1t = lds + W1B + W2B + w * 16 * HST;

  auto stage = [&](int nt) {
#pragma unroll
    for (int i = 0; i < 64 * CPR1 / 128; ++i) {
      int c = i * 128 + tid;
      int row = c / CPR1, lch = c % CPR1;
      int gch = (lch & ~7) | ((lch & 7) ^ (row & 7));
      const unsigned short* gp = Wa + (size_t)(nt * 64 + row) * K1 + gch * 8;
      __builtin_amdgcn_global_load_lds(
          (const __attribute__((address_space(1))) void*)gp,
          (__attribute__((address_space(3))) void*)(w1p + (i * 128 + w * 64) * 16), 16, 0, 0);
    }
#pragma unroll
    for (int i = 0; i < N2 * 8 / 128; ++i) {
      int c = i * 128 + tid;
      int row = c >> 3, lch = c & 7;
      int gch = lch ^ (row & 7);
      const unsigned short* gp = Wb + (size_t)row * 832 + nt * 64 + gch * 8;
      __builtin_amdgcn_global_load_lds(
          (const __attribute__((address_space(1))) void*)gp,
          (__attribute__((address_space(3))) void*)(w2s + (i * 128 + w * 64) * 16), 16, 0, 0);
    }
  };

  // ---- per-wave A band: 16 rows x K1 in registers ----
  bf16x8 af[KT1];
#pragma unroll
  for (int t = 0; t < KT1; ++t)
    af[t] = *reinterpret_cast<const bf16x8*>(
        A + (size_t)(m0 + lrow) * K1 + t * 32 + k16 * 8);

  stage(0);
  __syncthreads();

  f32x4 acc2[NOUT] = {};
  for (int nt = 0; nt < 13; ++nt) {
    // ---- gemm1: acc1 = Aband @ WaPanel^T ----
    f32x4 acc1[4] = {};
#pragma unroll
    for (int t = 0; t < KT1; ++t) {
      bf16x8 bf[4];
#pragma unroll
      for (int ni = 0; ni < 4; ++ni) {
        int row = ni * 16 + lrow;
        int ch = t * 4 + k16;
        int sc = (ch & ~7) | ((ch & 7) ^ (row & 7));
        bf[ni] = *reinterpret_cast<const bf16x8*>(w1p + row * ROWB1 + sc * 16);
      }
#pragma unroll
      for (int ni = 0; ni < 4; ++ni)
        acc1[ni] = __builtin_amdgcn_mfma_f32_16x16x32_bf16(af[t], bf[ni], acc1[ni], 0, 0, 0);
    }

    // ---- epilogue-1: relu(nd*acc1 + b) -> per-wave H tile (padded stride) ----
#pragma unroll
    for (int q = 0; q < 4; ++q) {
      int rl = k16 * 4 + q;
      float rs = nd[m0 + rl];
#pragma unroll
      for (int ni = 0; ni < 4; ++ni) {
        int colc = ni * 16 + lrow;
        int jg = nt * 64 + colc;
        float bb = (jg < 800) ? ba[jg] : 0.f;
        float v = fmaxf(acc1[ni][q] * rs + bb, 0.f);
        *(unsigned short*)(h1t + rl * HST + (colc >> 3) * 16 + (colc & 7) * 2) = f2bf(v);
      }
    }

    // ---- gemm2: acc2 += Htile @ WbSlice^T (same-wave LDS RAW via lgkmcnt) ----
#pragma unroll
    for (int ks = 0; ks < 2; ++ks) {
      bf16x8 a2 = *reinterpret_cast<const bf16x8*>(h1t + lrow * HST + (ks * 4 + k16) * 16);
#pragma unroll
      for (int ni = 0; ni < NOUT; ++ni) {
        int rc = ni * 16 + lrow;
        int sc = (ks * 4 + k16) ^ (rc & 7);
        bf16x8 b2v = *reinterpret_cast<const bf16x8*>(w2s + rc * 128 + sc * 16);
        acc2[ni] = __builtin_amdgcn_mfma_f32_16x16x32_bf16(a2, b2v, acc2[ni], 0, 0, 0);
      }
    }
    __syncthreads();
    if (nt + 1 < 13) {
      stage(nt + 1);
      __syncthreads();
    }
  }

  // ---- epilogue-2: Out = bf16(acc2 * ns[r]) ----
#pragma unroll
  for (int q = 0; q < 4; ++q) {
    int r = m0 + k16 * 4 + q;
    if (r >= M) continue;
    float sn = ns[r];
#pragma unroll
    for (int ni = 0; ni < NOUT; ++ni) {
      int c = ni * 16 + lrow;
      Out[(size_t)r * N2 + c] = f2bf(acc2[ni][q] * sn);
    }
  }
}

extern "C" void kernel_launch(void* const* d_in, const int* in_sizes, int n_in,
                              void* d_out, int out_size, void* d_ws, size_t ws_size,
                              hipStream_t stream) {
  const float* x  = (const float*)d_in[0];
  const int* src  = (const int*)d_in[1];
  const int* dst  = (const int*)d_in[2];
  const float* W1 = (const float*)d_in[3];
  const float* b1 = (const float*)d_in[4];
  const float* W2 = (const float*)d_in[5];
  const float* b2 = (const float*)d_in[6];
  const float* W3 = (const float*)d_in[7];
  const float* b3 = (const float*)d_in[8];
  const float* W4 = (const float*)d_in[9];
  const float* b4 = (const float*)d_in[10];

  float* out_enc = (float*)d_out;                  // [NN,128]
  float* out_dec = out_enc + (size_t)NN * 128;     // [NN,256]

  // ---- workspace layout (~50 MB) ----
  float* ns = (float*)d_ws;                        // [NN]
  float* nd = ns + NN;                             // [NN]
  unsigned short* xb  = (unsigned short*)(nd + NN);  // [NN*256]
  unsigned short* T2b = xb + (size_t)NN * 256;     // [NN*128] bf16 (L1+L2 out)
  unsigned short* h2  = T2b + (size_t)NN * 128;    // [NN*128] bf16 (h2*ns)
  unsigned short* A1  = h2 + (size_t)NN * 128;     // [MROWS*256]
  unsigned short* A3  = A1 + (size_t)MROWS * 256;  // [MROWS*128]
  unsigned short* G4  = A3 + (size_t)MROWS * 128;  // [NN*256] bf16 (L3+L4 out)
  unsigned short* W1t = G4 + (size_t)NN * 256;     // [832*256]
  unsigned short* W2t = W1t + 832 * 256;           // [128*832]
  unsigned short* W3t = W2t + 128 * 832;           // [832*128]
  unsigned short* W4t = W3t + 832 * 128;           // [256*832]
  int* degs   = (int*)(W4t + 256 * 832);           // [NN]
  int* degd   = degs + NN;                         // [NN]
  int* cursor = degd + NN;                         // [NN]
  int* rowptr = cursor + NN;                       // [NN+1]
  int* col    = rowptr + NN + 1;                   // [NE]
  int* pscan  = col + NE;                          // [NN]
  int* bsum   = pscan + NN;                        // [SB]

  // ---- CSR build + norms (parallel scan) ----
  zero_kernel<<<(3 * NN / 4 + 255) / 256, 256, 0, stream>>>((int4*)degs, 3 * NN / 4);
  deg_count_kernel<<<(NE + 255) / 256, 256, 0, stream>>>(src, dst, degs, degd, NE);
  pscan_norm_kernel<<<SB, 256, 0, stream>>>(degs, degd, pscan, bsum, ns, nd, NN);
  rowptr_fix_kernel<<<SB, 256, 0, stream>>>(pscan, bsum, rowptr, NN);
  csr_fill_kernel<<<(NE + 255) / 256, 256, 0, stream>>>(src, dst, rowptr, cursor, col, NE);

  // ---- weight conversion: tiled transpose, coalesced both sides ----
  wt_tconv_kernel<<<624, 256, 0, stream>>>(W1, W2, W3, W4, W1t, W2t, W3t, W4t);

  // ---- L1+L2 fused: xb -> gather -> A1; gemm9v3<8,8> -> T2b ----
  scale_cvt_kernel<<<(NN * 32 + 255) / 256, 256, 0, stream>>>(x, ns, xb);
  gatherb_kernel<256, 0><<<(NN + 7) / 8, 256, 0, stream>>>(
      xb, rowptr, col, nullptr, nullptr, nullptr, A1, nullptr, NN);
  gemm9v3_kernel<8, 8><<<628, 128, 0, stream>>>(A1, W1t, W2t, T2b, NN, nd, ns, b1);

  // ---- L2 gather: -> h2s=bf16(h2*ns) + sigmoid(out_enc) ----
  gatherb_kernel<128, 1><<<(NN + 15) / 16, 256, 0, stream>>>(
      T2b, rowptr, col, nd, b2, ns, h2, out_enc, NN);

  // ---- L3+L4 fused: gather(h2s) -> A3; gemm9v3<4,16> -> G4 ----
  gatherb_kernel<128, 0><<<(NN + 15) / 16, 256, 0, stream>>>(
      h2, rowptr, col, nullptr, nullptr, nullptr, A3, nullptr, NN);
  gemm9v3_kernel<4, 16><<<628, 128, 0, stream>>>(A3, W3t, W4t, G4, NN, nd, ns, b3);

  // ---- L4 gather: -> sigmoid(out_dec) ----
  gatherb_kernel<256, 2><<<(NN + 7) / 8, 256, 0, stream>>>(
      G4, rowptr, col, nd, b4, nullptr, nullptr, out_dec, NN);
}